// Round 10
// baseline (144.092 us; speedup 1.0000x reference)
//
#include <hip/hip_runtime.h>
#include <hip/hip_bf16.h>

typedef __attribute__((ext_vector_type(8))) short bf16x8;
typedef __attribute__((ext_vector_type(4))) float f32x4;

__device__ __forceinline__ float bf2f(unsigned short u) {
    union { unsigned int i; float f; } c; c.i = ((unsigned int)u) << 16; return c.f;
}
__device__ __forceinline__ unsigned short f2bf(float f) {
    union { float f; unsigned int i; } c; c.f = f;
    unsigned int x = c.i;
    x += 0x7fffu + ((x >> 16) & 1u);   // round-to-nearest-even
    return (unsigned short)(x >> 16);
}
// pack two f32 -> u32 of 2 bf16 (RNE), elem0 in low half
__device__ __forceinline__ unsigned int pk2(float a, float b) {
    __hip_bfloat162 h = __float22bfloat162_rn(float2{a, b});
    union { __hip_bfloat162 h; unsigned int u; } c; c.h = h; return c.u;
}
__device__ __forceinline__ float tanh_fast(float v) {
    float a = fabsf(v);
    a = fminf(a, 15.0f);
    float e = __expf(2.0f * a);
    float t = 1.0f - 2.0f / (e + 1.0f);
    return copysignf(t, v);
}

// async global->LDS, 16B per lane; lptr must be wave-uniform, gptr per-lane
#define GLOAD_LDS16(gp, lp) \
    __builtin_amdgcn_global_load_lds((const __attribute__((address_space(1))) void*)(gp), \
                                     (__attribute__((address_space(3))) void*)(lp), 16, 0, 0)

#define MFMA(a, b, c) __builtin_amdgcn_mfma_f32_16x16x32_bf16((a), (b), (c), 0, 0, 0)

#define SBAR()  __builtin_amdgcn_s_barrier()
#define SCHED0() __builtin_amdgcn_sched_barrier(0)

// ---------------- k_pre: fused {sumxp | prepA | conv_W} ----------------
// bid <  256 : sumxp   (b = bid>>4, tc = bid&15)
// bid <  768 : prepA   (i = bid-256)
// bid < 1792 : conv_W  (idx = bid-768; e0 = (idx&31)*16, j0 = (idx>>5)*32)
__global__ void k_pre(const float* __restrict__ x, const float* __restrict__ m1w,
                      const float* __restrict__ bent, const float* __restrict__ W,
                      float* __restrict__ sumxp, unsigned short* __restrict__ Abf,
                      float* __restrict__ bias2, unsigned short* __restrict__ WT) {
    __shared__ float tile[128][33];
    __shared__ float r4[4];
    int bid = blockIdx.x;
    int tid = threadIdx.x;
    if (bid < 256) {
        int b = bid >> 4, tc = bid & 15;
        const float* xp = x + ((size_t)b * 1024 + tc * 64) * 512;
        float a0 = 0.f, a1 = 0.f;
        for (int t = 0; t < 64; ++t) {
            a0 += xp[(size_t)t * 512 + tid];
            a1 += xp[(size_t)t * 512 + tid + 256];
        }
        float* o = sumxp + (size_t)(b * 16 + tc) * 512;
        o[tid] = a0;
        o[tid + 256] = a1;
    } else if (bid < 768) {
        int i = bid - 256;
        const float* row = m1w + (size_t)i * 4096;
        float acc = 0.f;
        #pragma unroll
        for (int q = 0; q < 4; ++q) {
            int col = q * 1024 + tid * 4;
            float4 v = *(const float4*)(row + col);
            ushort4 o;
            o.x = f2bf(v.x); o.y = f2bf(v.y); o.z = f2bf(v.z); o.w = f2bf(v.w);
            *(ushort4*)(Abf + (size_t)i * 4096 + col) = o;
            int e0 = col >> 3, s0 = col & 7;
            acc += v.x * bent[(s0    ) * 512 + e0];
            acc += v.y * bent[(s0 + 1) * 512 + e0];
            acc += v.z * bent[(s0 + 2) * 512 + e0];
            acc += v.w * bent[(s0 + 3) * 512 + e0];
        }
        #pragma unroll
        for (int off = 32; off; off >>= 1) acc += __shfl_xor(acc, off);
        if ((tid & 63) == 0) r4[tid >> 6] = acc;
        __syncthreads();
        if (tid == 0) bias2[i] = r4[0] + r4[1] + r4[2] + r4[3];
    } else {
        int idx = bid - 768;
        int e0 = (idx & 31) * 16;
        int j0 = (idx >> 5) * 32;
        int tx = tid & 31, ty = tid >> 5;
        #pragma unroll
        for (int q = 0; q < 16; ++q) {
            int lk = q * 8 + ty;
            int de = lk >> 3, s = lk & 7;
            int r = s * 512 + e0 + de;
            tile[lk][tx] = W[(size_t)r * 1024 + j0 + tx];
        }
        __syncthreads();
        int j = tid >> 3, ck = (tid & 7) * 16;
        unsigned short* dst = WT + (size_t)(j0 + j) * 4096 + e0 * 8 + ck;
        #pragma unroll
        for (int g = 0; g < 4; ++g) {
            ushort4 o;
            o.x = f2bf(tile[ck + g * 4 + 0][j]);
            o.y = f2bf(tile[ck + g * 4 + 1][j]);
            o.z = f2bf(tile[ck + g * 4 + 2][j]);
            o.w = f2bf(tile[ck + g * 4 + 3][j]);
            *(ushort4*)(dst + g * 4) = o;
        }
    }
}

// ---------------- GEMM1 (split-K=8, pipelined): C[i,j] = sum_k Abf[i,k] WT[j,k] ----------------
__launch_bounds__(512, 2)
__global__ void k_gemm1(const unsigned short* __restrict__ Abf,
                        const unsigned short* __restrict__ WT,
                        float* __restrict__ CpL, float* __restrict__ CpR) {
    __shared__ __align__(16) unsigned short sA[2][64 * 64];
    __shared__ __align__(16) unsigned short sB[2][256 * 64];
    int i0 = blockIdx.x * 64;
    int j0 = blockIdx.y * 256;
    int kbase = blockIdx.z * 512;
    int tid = threadIdx.x, lane = tid & 63, w = tid >> 6;
    int wm = w >> 2, wn = w & 3;
    int lr = lane >> 3, sl = lane & 7;
    int lo = lane & 15, hi = lane >> 4;
    int arow = w * 8 + lr;
    const unsigned short* gA = Abf + (size_t)(i0 + arow) * 4096 + kbase + ((sl ^ lr) << 3);
    const unsigned short* gB0 = WT + (size_t)(j0 + w * 32 + 0 * 8 + lr) * 4096 + kbase + ((sl ^ lr) << 3);
    const unsigned short* gB1 = WT + (size_t)(j0 + w * 32 + 1 * 8 + lr) * 4096 + kbase + ((sl ^ lr) << 3);
    const unsigned short* gB2 = WT + (size_t)(j0 + w * 32 + 2 * 8 + lr) * 4096 + kbase + ((sl ^ lr) << 3);
    const unsigned short* gB3 = WT + (size_t)(j0 + w * 32 + 3 * 8 + lr) * 4096 + kbase + ((sl ^ lr) << 3);
    bool left = (blockIdx.y < 2);
    f32x4 acc[2][4] = {};

#define G1_STAGE(tt, bufn)                                                    \
    do {                                                                      \
        int koff = (tt) * 64;                                                 \
        GLOAD_LDS16(gA + koff, &sA[bufn][w * 8 * 64]);                        \
        GLOAD_LDS16(gB0 + koff, &sB[bufn][(w * 32 + 0) * 64]);                \
        GLOAD_LDS16(gB1 + koff, &sB[bufn][(w * 32 + 8) * 64]);                \
        GLOAD_LDS16(gB2 + koff, &sB[bufn][(w * 32 + 16) * 64]);               \
        GLOAD_LDS16(gB3 + koff, &sB[bufn][(w * 32 + 24) * 64]);               \
        SCHED0();                                                             \
    } while (0)

    G1_STAGE(0, 0);
    #pragma unroll
    for (int t = 0; t < 8; ++t) {
        int buf = t & 1;
        if (t < 7) {
            G1_STAGE(t + 1, buf ^ 1);
            asm volatile("s_waitcnt vmcnt(5)" ::: "memory");
        } else {
            asm volatile("s_waitcnt vmcnt(0)" ::: "memory");
        }
        SCHED0(); SBAR(); SCHED0();
        __builtin_amdgcn_s_setprio(1);
        #pragma unroll
        for (int kk = 0; kk < 2; ++kk) {
            int slotX = ((kk * 4 + hi) ^ (lo & 7)) << 3;
            bf16x8 a0 = *(const bf16x8*)(&sA[buf][(wm * 32 +      lo) * 64 + slotX]);
            bf16x8 a1 = *(const bf16x8*)(&sA[buf][(wm * 32 + 16 + lo) * 64 + slotX]);
            #pragma unroll
            for (int n = 0; n < 4; ++n) {
                bf16x8 bb = *(const bf16x8*)(&sB[buf][(wn * 64 + n * 16 + lo) * 64 + slotX]);
                if (left) {
                    acc[0][n] = MFMA(a0, bb, acc[0][n]);
                    acc[1][n] = MFMA(a1, bb, acc[1][n]);
                } else {
                    acc[0][n] = MFMA(bb, a0, acc[0][n]);
                    acc[1][n] = MFMA(bb, a1, acc[1][n]);
                }
            }
        }
        __builtin_amdgcn_s_setprio(0);
        if (t < 7) { SCHED0(); SBAR(); SCHED0(); }
    }
#undef G1_STAGE

    int ksoff = blockIdx.z * 262144;
    if (left) {
        #pragma unroll
        for (int m = 0; m < 2; ++m) {
            int ib = i0 + wm * 32 + m * 16 + hi * 4;
            #pragma unroll
            for (int n = 0; n < 4; ++n) {
                int j = j0 + wn * 64 + n * 16 + lo;
                #pragma unroll
                for (int r = 0; r < 4; ++r)
                    CpL[ksoff + (ib + r) * 512 + j] = acc[m][n][r];
            }
        }
    } else {
        #pragma unroll
        for (int m = 0; m < 2; ++m) {
            int ic = i0 + wm * 32 + m * 16 + lo;
            #pragma unroll
            for (int n = 0; n < 4; ++n) {
                int db = j0 - 512 + wn * 64 + n * 16 + hi * 4;
                #pragma unroll
                for (int r = 0; r < 4; ++r)
                    CpR[ksoff + (db + r) * 512 + ic] = acc[m][n][r];
            }
        }
    }
}

// ---------------- k_mid: fused {reduce-M1 | cb} ----------------
// bid < 256: M1bf[gid] = bf16(sum_ks CpL);  bid >= 256: cb from CpR partials directly.
__global__ void k_mid(const float* __restrict__ CpL, const float* __restrict__ CpR,
                      const float* __restrict__ sumxp, const float* __restrict__ bias2,
                      const float* __restrict__ m1b,
                      unsigned short* __restrict__ M1bf, float* __restrict__ cbo) {
    __shared__ float sSx[512];
    __shared__ float sPart[4][64];
    int bid = blockIdx.x;
    int tid = threadIdx.x;
    if (bid < 256) {
        int gid = bid * 256 + tid;
        float4 s = ((const float4*)CpL)[gid];
        #pragma unroll
        for (int ks = 1; ks < 8; ++ks) {
            float4 t = ((const float4*)CpL)[ks * 65536 + gid];
            s.x += t.x; s.y += t.y; s.z += t.z; s.w += t.w;
        }
        ushort4 o;
        o.x = f2bf(s.x); o.y = f2bf(s.y); o.z = f2bf(s.z); o.w = f2bf(s.w);
        ((ushort4*)M1bf)[gid] = o;
    } else {
        int bb = bid - 256;               // 0..127
        int b = bb >> 3, i0 = (bb & 7) * 64;
        for (int d = tid; d < 512; d += 256) {
            float s = 0.f;
            #pragma unroll
            for (int p = 0; p < 16; ++p)
                s += sumxp[(size_t)(b * 16 + p) * 512 + d];
            sSx[d] = s;
        }
        __syncthreads();
        int il = tid & 63, dq = tid >> 6;
        float acc = 0.f;
        #pragma unroll 1
        for (int ks = 0; ks < 8; ++ks) {
            const float* cp = CpR + (size_t)ks * 262144 + (size_t)(dq * 128) * 512 + i0 + il;
            #pragma unroll 4
            for (int dd = 0; dd < 128; ++dd)
                acc += sSx[dq * 128 + dd] * cp[(size_t)dd * 512];
        }
        sPart[dq][il] = acc;
        __syncthreads();
        if (tid < 64) {
            float v = sPart[0][tid] + sPart[1][tid] + sPart[2][tid] + sPart[3][tid];
            cbo[b * 512 + i0 + tid] = v * (1.0f / 1024.0f) + bias2[i0 + tid] + m1b[i0 + tid];
        }
    }
}

// ---------------- GEMM2 (K-loop only), 32-row tiles, 512 blocks x 256 thr, 2 blocks/CU ----
// y[bt,i] = sum_d x[bt,d]*M1[i,d]  (cb added in k_lnlogit)
// ypk per block: chunk c = (w*2+m)*8+n (256 elems), elem (hi*16+lo)*4+r
//   -> row bt0 + m*16 + hi*4 + r, col w*128 + n*16 + lo
__launch_bounds__(256, 2)
__global__ void k_gemm2s(const float* __restrict__ x,
                         const unsigned short* __restrict__ M1bf,
                         unsigned short* __restrict__ ypk) {
    __shared__ __align__(16) unsigned short sA[32 * 64];    // 4 KB
    __shared__ __align__(16) unsigned short sB[512 * 64];   // 64 KB
    int bt0 = blockIdx.x * 32;
    int tid = threadIdx.x, lane = tid & 63, w = tid >> 6;   // 4 waves
    int lo = lane & 15, hi = lane >> 4;
    int lr = lane >> 3, sl = lane & 7;
    int arow = tid >> 3, aslot = tid & 7;                    // 32 rows x 8 slots
    const float* gA = x + (size_t)(bt0 + arow) * 512 + aslot * 8;
    unsigned short* dAp = sA + arow * 64 + ((aslot ^ (arow & 7)) << 3);
    const unsigned short* gB[16];
    #pragma unroll
    for (int g = 0; g < 16; ++g)
        gB[g] = M1bf + (size_t)(w * 128 + g * 8 + lr) * 512 + ((sl ^ lr) << 3);
    f32x4 acc[2][8] = {};
    for (int k0 = 0; k0 < 512; k0 += 64) {
        if (k0) __syncthreads();
        #pragma unroll
        for (int g = 0; g < 16; ++g)
            GLOAD_LDS16(gB[g] + k0, &sB[(w * 128 + g * 8) * 64]);
        float4 f0 = *(const float4*)(gA + k0);
        float4 f1 = *(const float4*)(gA + k0 + 4);
        bf16x8 pk;
        pk[0] = (short)f2bf(f0.x); pk[1] = (short)f2bf(f0.y);
        pk[2] = (short)f2bf(f0.z); pk[3] = (short)f2bf(f0.w);
        pk[4] = (short)f2bf(f1.x); pk[5] = (short)f2bf(f1.y);
        pk[6] = (short)f2bf(f1.z); pk[7] = (short)f2bf(f1.w);
        *(bf16x8*)dAp = pk;
        __syncthreads();
        #pragma unroll
        for (int kk = 0; kk < 2; ++kk) {
            int slotX = ((kk * 4 + hi) ^ (lo & 7)) << 3;
            bf16x8 a0 = *(const bf16x8*)(sA + (     lo) * 64 + slotX);
            bf16x8 a1 = *(const bf16x8*)(sA + (16 + lo) * 64 + slotX);
            #pragma unroll
            for (int n = 0; n < 8; ++n) {
                bf16x8 bb = *(const bf16x8*)(sB + (w * 128 + n * 16 + lo) * 64 + slotX);
                acc[0][n] = MFMA(a0, bb, acc[0][n]);
                acc[1][n] = MFMA(a1, bb, acc[1][n]);
            }
        }
    }
    unsigned short* yb = ypk + (size_t)blockIdx.x * 16384;
    #pragma unroll
    for (int m = 0; m < 2; ++m) {
        #pragma unroll
        for (int n = 0; n < 8; ++n) {
            unsigned int u0 = pk2(acc[m][n][0], acc[m][n][1]);
            unsigned int u1 = pk2(acc[m][n][2], acc[m][n][3]);
            uint2 o; o.x = u0; o.y = u1;
            *(uint2*)(yb + ((((w * 2 + m) * 8 + n) << 8) + (lane << 2))) = o;
        }
    }
}

// ---------------- LN + tanh + logit (32-row blocks, 512 x 256 thr) ----------------
__launch_bounds__(256)
__global__ void k_lnlogit(const unsigned short* __restrict__ ypk,
                          const float* __restrict__ cb,
                          const float* __restrict__ lng, const float* __restrict__ lnb,
                          const float* __restrict__ m2w, const float* __restrict__ m2b,
                          float* __restrict__ logits) {
    __shared__ __align__(16) unsigned short sY[16384];   // 32 KB
    __shared__ float sCb[512], sG[512], sBe[512], sW[512];
    __shared__ float sS1[32][8], sS2[32][8], sLg[32][8];
    int blk = blockIdx.x;
    int bt0 = blk * 32;
    int b = bt0 >> 10;
    int tid = threadIdx.x, w = tid >> 6, lane = tid & 63;
    #pragma unroll
    for (int q = 0; q < 2; ++q) {
        int c = q * 256 + tid;
        sCb[c] = cb[b * 512 + c];
        sG[c]  = lng[c];
        sBe[c] = lnb[c];
        sW[c]  = m2w[c];
    }
    const unsigned short* src = ypk + (size_t)blk * 16384;
    #pragma unroll
    for (int it = 0; it < 8; ++it) {
        int off = (w * 8 + it) * 512;           // 4 waves x 8 iters x 1KB = 32KB
        GLOAD_LDS16(src + off + (lane << 3), &sY[off]);
    }
    asm volatile("s_waitcnt vmcnt(0)" ::: "memory");
    __syncthreads();

    int row = tid >> 3, sub = tid & 7;           // 32 rows x 8 col-groups
    int m = row >> 4, hi = (row >> 2) & 3, r = row & 3;
    float s1 = 0.f, s2 = 0.f;
    #pragma unroll
    for (int wn = 0; wn < 4; ++wn) {
        #pragma unroll
        for (int n = 0; n < 8; ++n) {
            int c = (wn * 2 + m) * 8 + n;
            int eb = c * 256 + r;
            int ib = wn * 128 + n * 16;
            #pragma unroll
            for (int l2 = 0; l2 < 2; ++l2) {
                int lo = sub * 2 + l2;
                float v = bf2f(sY[eb + (hi * 16 + lo) * 4]) + sCb[ib + lo];
                s1 += v; s2 += v * v;
            }
        }
    }
    sS1[row][sub] = s1; sS2[row][sub] = s2;
    __syncthreads();
    float a1 = 0.f, a2 = 0.f;
    #pragma unroll
    for (int q = 0; q < 8; ++q) { a1 += sS1[row][q]; a2 += sS2[row][q]; }
    float mu = a1 * (1.0f / 512.0f);
    float var = a2 * (1.0f / 512.0f) - mu * mu;
    float rs = rsqrtf(var + 1e-5f);
    float lg = 0.f;
    #pragma unroll
    for (int wn = 0; wn < 4; ++wn) {
        #pragma unroll
        for (int n = 0; n < 8; ++n) {
            int c = (wn * 2 + m) * 8 + n;
            int eb = c * 256 + r;
            int ib = wn * 128 + n * 16;
            #pragma unroll
            for (int l2 = 0; l2 < 2; ++l2) {
                int lo = sub * 2 + l2;
                float v = bf2f(sY[eb + (hi * 16 + lo) * 4]) + sCb[ib + lo];
                float h = tanh_fast((v - mu) * rs * sG[ib + lo] + sBe[ib + lo]);
                lg += h * sW[ib + lo];
            }
        }
    }
    sLg[row][sub] = lg;
    __syncthreads();
    if (sub == 0) {
        float t = 0.f;
        #pragma unroll
        for (int q = 0; q < 8; ++q) t += sLg[row][q];
        logits[bt0 + row] = t + m2b[0];
    }
}

// ---------------- softmax (per-block recompute) + context partials ----------------
__global__ void k_swctx(const float* __restrict__ x, const float* __restrict__ logits,
                        float* __restrict__ ctxp, float* __restrict__ attn) {
    int b = blockIdx.x, tc = blockIdx.y;
    int tid = threadIdx.x;
    __shared__ float red[4];
    __shared__ float sWt[1024];
    float4 v = ((const float4*)(logits + b * 1024))[tid];
    float mx = fmaxf(fmaxf(v.x, v.y), fmaxf(v.z, v.w));
    for (int off = 32; off; off >>= 1) mx = fmaxf(mx, __shfl_xor(mx, off));
    if ((tid & 63) == 0) red[tid >> 6] = mx;
    __syncthreads();
    mx = fmaxf(fmaxf(red[0], red[1]), fmaxf(red[2], red[3]));
    float e0 = expf(v.x - mx), e1 = expf(v.y - mx), e2 = expf(v.z - mx), e3 = expf(v.w - mx);
    float sm = e0 + e1 + e2 + e3;
    for (int off = 32; off; off >>= 1) sm += __shfl_xor(sm, off);
    __syncthreads();
    if ((tid & 63) == 0) red[tid >> 6] = sm;
    __syncthreads();
    float inv = 1.0f / (red[0] + red[1] + red[2] + red[3]);
    float4 o; o.x = e0 * inv; o.y = e1 * inv; o.z = e2 * inv; o.w = e3 * inv;
    ((float4*)sWt)[tid] = o;
    if (tc == 0) ((float4*)(attn + b * 1024))[tid] = o;
    __syncthreads();
    const float* xp = x + ((size_t)b * 1024 + tc * 64) * 512;
    const float* wp = sWt + tc * 64;
    float a0 = 0.f, a1 = 0.f;
    for (int t = 0; t < 64; ++t) {
        float wv = wp[t];
        a0 += wv * xp[(size_t)t * 512 + tid];
        a1 += wv * xp[(size_t)t * 512 + tid + 256];
    }
    float* op = ctxp + (size_t)(b * 16 + tc) * 512;
    op[tid] = a0;
    op[tid + 256] = a1;
}

// context[b][d] = sum of 16 partials
__global__ void k_ctxred(const float* __restrict__ ctxp, float* __restrict__ ctx) {
    int idx = blockIdx.x * 256 + threadIdx.x;   // 8192
    int b = idx >> 9, d = idx & 511;
    float s = 0.f;
    #pragma unroll
    for (int p = 0; p < 16; ++p)
        s += ctxp[(size_t)(b * 16 + p) * 512 + d];
    ctx[b * 512 + d] = s;
}

// ---------------- launch ----------------
extern "C" void kernel_launch(void* const* d_in, const int* in_sizes, int n_in,
                              void* d_out, int out_size, void* d_ws, size_t ws_size,
                              hipStream_t stream) {
    (void)in_sizes; (void)n_in; (void)out_size; (void)ws_size;
    const float* x    = (const float*)d_in[0];
    const float* Went = (const float*)d_in[1];
    const float* bent = (const float*)d_in[2];
    const float* m1w  = (const float*)d_in[3];
    const float* m1b  = (const float*)d_in[4];
    const float* lng  = (const float*)d_in[5];
    const float* lnb  = (const float*)d_in[6];
    const float* m2w  = (const float*)d_in[7];
    const float* m2b  = (const float*)d_in[8];
    float* out = (float*)d_out;            // [0,8192): context ; [8192,24576): attn
    char* ws = (char*)d_ws;

    unsigned short* Abf   = (unsigned short*)(ws);                        // 4 MB
    unsigned short* WT    = (unsigned short*)(ws + 4194304);              // 8 MB
    float* CpL            = (float*)(ws + 12582912);                      // 8 MB
    float* CpR            = (float*)(ws + 20971520);                      // 8 MB
    unsigned short* ypk   = (unsigned short*)(ws + 12582912);             // 16 MB (reuses CpL/CpR after k_mid)
    unsigned short* M1bf  = (unsigned short*)(ws + 29360128);             // 512 KB
    float* sumxp  = (float*)(ws + 29884416);                              // 512 KB
    float* ctxp   = (float*)(ws + 30408704);                              // 512 KB
    float* bias2  = (float*)(ws + 30932992);                              // 2 KB
    float* cb     = (float*)(ws + 30935040);                              // 32 KB
    float* logits = (float*)(ws + 30967808);                              // 64 KB

    k_pre<<<1792, 256, 0, stream>>>(x, m1w, bent, Went, sumxp, Abf, bias2, WT);
    k_gemm1<<<dim3(8, 4, 8), 512, 0, stream>>>(Abf, WT, CpL, CpR);
    k_mid<<<384, 256, 0, stream>>>(CpL, CpR, sumxp, bias2, m1b, M1bf, cb);
    k_gemm2s<<<512, 256, 0, stream>>>(x, M1bf, ypk);
    k_lnlogit<<<512, 256, 0, stream>>>(ypk, cb, lng, lnb, m2w, m2b, logits);
    k_swctx<<<dim3(16, 16), 256, 0, stream>>>(x, logits, ctxp, out + 8192);
    k_ctxred<<<32, 256, 0, stream>>>(ctxp, out);
}

// Round 11
// 88.201 us; speedup vs baseline: 1.6337x; 1.6337x over previous
//
#include <hip/hip_runtime.h>
#include <hip/hip_bf16.h>

typedef __attribute__((ext_vector_type(8))) short bf16x8;
typedef __attribute__((ext_vector_type(4))) float f32x4;

__device__ __forceinline__ float bf2f(unsigned short u) {
    union { unsigned int i; float f; } c; c.i = ((unsigned int)u) << 16; return c.f;
}
__device__ __forceinline__ unsigned short f2bf(float f) {
    union { float f; unsigned int i; } c; c.f = f;
    unsigned int x = c.i;
    x += 0x7fffu + ((x >> 16) & 1u);   // round-to-nearest-even
    return (unsigned short)(x >> 16);
}
// pack two f32 -> u32 of 2 bf16 (RNE), elem0 in low half
__device__ __forceinline__ unsigned int pk2(float a, float b) {
    __hip_bfloat162 h = __float22bfloat162_rn(float2{a, b});
    union { __hip_bfloat162 h; unsigned int u; } c; c.h = h; return c.u;
}
__device__ __forceinline__ float tanh_fast(float v) {
    float a = fabsf(v);
    a = fminf(a, 15.0f);
    float e = __expf(2.0f * a);
    float t = 1.0f - 2.0f / (e + 1.0f);
    return copysignf(t, v);
}

// async global->LDS, 16B per lane; lptr must be wave-uniform, gptr per-lane
#define GLOAD_LDS16(gp, lp) \
    __builtin_amdgcn_global_load_lds((const __attribute__((address_space(1))) void*)(gp), \
                                     (__attribute__((address_space(3))) void*)(lp), 16, 0, 0)

#define MFMA(a, b, c) __builtin_amdgcn_mfma_f32_16x16x32_bf16((a), (b), (c), 0, 0, 0)

#define SBAR()  __builtin_amdgcn_s_barrier()
#define SCHED0() __builtin_amdgcn_sched_barrier(0)

// ---------------- k_pre: fused {sumxp | prepA | conv_W} ----------------
__global__ void k_pre(const float* __restrict__ x, const float* __restrict__ m1w,
                      const float* __restrict__ bent, const float* __restrict__ W,
                      float* __restrict__ sumxp, unsigned short* __restrict__ Abf,
                      float* __restrict__ bias2, unsigned short* __restrict__ WT) {
    __shared__ float tile[128][33];
    __shared__ float r4[4];
    int bid = blockIdx.x;
    int tid = threadIdx.x;
    if (bid < 256) {
        int b = bid >> 4, tc = bid & 15;
        const float* xp = x + ((size_t)b * 1024 + tc * 64) * 512;
        float a0 = 0.f, a1 = 0.f;
        for (int t = 0; t < 64; ++t) {
            a0 += xp[(size_t)t * 512 + tid];
            a1 += xp[(size_t)t * 512 + tid + 256];
        }
        float* o = sumxp + (size_t)(b * 16 + tc) * 512;
        o[tid] = a0;
        o[tid + 256] = a1;
    } else if (bid < 768) {
        int i = bid - 256;
        const float* row = m1w + (size_t)i * 4096;
        float acc = 0.f;
        #pragma unroll
        for (int q = 0; q < 4; ++q) {
            int col = q * 1024 + tid * 4;
            float4 v = *(const float4*)(row + col);
            ushort4 o;
            o.x = f2bf(v.x); o.y = f2bf(v.y); o.z = f2bf(v.z); o.w = f2bf(v.w);
            *(ushort4*)(Abf + (size_t)i * 4096 + col) = o;
            int e0 = col >> 3, s0 = col & 7;
            acc += v.x * bent[(s0    ) * 512 + e0];
            acc += v.y * bent[(s0 + 1) * 512 + e0];
            acc += v.z * bent[(s0 + 2) * 512 + e0];
            acc += v.w * bent[(s0 + 3) * 512 + e0];
        }
        #pragma unroll
        for (int off = 32; off; off >>= 1) acc += __shfl_xor(acc, off);
        if ((tid & 63) == 0) r4[tid >> 6] = acc;
        __syncthreads();
        if (tid == 0) bias2[i] = r4[0] + r4[1] + r4[2] + r4[3];
    } else {
        int idx = bid - 768;
        int e0 = (idx & 31) * 16;
        int j0 = (idx >> 5) * 32;
        int tx = tid & 31, ty = tid >> 5;
        #pragma unroll
        for (int q = 0; q < 16; ++q) {
            int lk = q * 8 + ty;
            int de = lk >> 3, s = lk & 7;
            int r = s * 512 + e0 + de;
            tile[lk][tx] = W[(size_t)r * 1024 + j0 + tx];
        }
        __syncthreads();
        int j = tid >> 3, ck = (tid & 7) * 16;
        unsigned short* dst = WT + (size_t)(j0 + j) * 4096 + e0 * 8 + ck;
        #pragma unroll
        for (int g = 0; g < 4; ++g) {
            ushort4 o;
            o.x = f2bf(tile[ck + g * 4 + 0][j]);
            o.y = f2bf(tile[ck + g * 4 + 1][j]);
            o.z = f2bf(tile[ck + g * 4 + 2][j]);
            o.w = f2bf(tile[ck + g * 4 + 3][j]);
            *(ushort4*)(dst + g * 4) = o;
        }
    }
}

// ---------------- GEMM1 (split-K=8, pipelined): C[i,j] = sum_k Abf[i,k] WT[j,k] ----------------
__launch_bounds__(512, 2)
__global__ void k_gemm1(const unsigned short* __restrict__ Abf,
                        const unsigned short* __restrict__ WT,
                        float* __restrict__ CpL, float* __restrict__ CpR) {
    __shared__ __align__(16) unsigned short sA[2][64 * 64];
    __shared__ __align__(16) unsigned short sB[2][256 * 64];
    int i0 = blockIdx.x * 64;
    int j0 = blockIdx.y * 256;
    int kbase = blockIdx.z * 512;
    int tid = threadIdx.x, lane = tid & 63, w = tid >> 6;
    int wm = w >> 2, wn = w & 3;
    int lr = lane >> 3, sl = lane & 7;
    int lo = lane & 15, hi = lane >> 4;
    int arow = w * 8 + lr;
    const unsigned short* gA = Abf + (size_t)(i0 + arow) * 4096 + kbase + ((sl ^ lr) << 3);
    const unsigned short* gB0 = WT + (size_t)(j0 + w * 32 + 0 * 8 + lr) * 4096 + kbase + ((sl ^ lr) << 3);
    const unsigned short* gB1 = WT + (size_t)(j0 + w * 32 + 1 * 8 + lr) * 4096 + kbase + ((sl ^ lr) << 3);
    const unsigned short* gB2 = WT + (size_t)(j0 + w * 32 + 2 * 8 + lr) * 4096 + kbase + ((sl ^ lr) << 3);
    const unsigned short* gB3 = WT + (size_t)(j0 + w * 32 + 3 * 8 + lr) * 4096 + kbase + ((sl ^ lr) << 3);
    bool left = (blockIdx.y < 2);
    f32x4 acc[2][4] = {};

#define G1_STAGE(tt, bufn)                                                    \
    do {                                                                      \
        int koff = (tt) * 64;                                                 \
        GLOAD_LDS16(gA + koff, &sA[bufn][w * 8 * 64]);                        \
        GLOAD_LDS16(gB0 + koff, &sB[bufn][(w * 32 + 0) * 64]);                \
        GLOAD_LDS16(gB1 + koff, &sB[bufn][(w * 32 + 8) * 64]);                \
        GLOAD_LDS16(gB2 + koff, &sB[bufn][(w * 32 + 16) * 64]);               \
        GLOAD_LDS16(gB3 + koff, &sB[bufn][(w * 32 + 24) * 64]);               \
        SCHED0();                                                             \
    } while (0)

    G1_STAGE(0, 0);
    #pragma unroll
    for (int t = 0; t < 8; ++t) {
        int buf = t & 1;
        if (t < 7) {
            G1_STAGE(t + 1, buf ^ 1);
            asm volatile("s_waitcnt vmcnt(5)" ::: "memory");
        } else {
            asm volatile("s_waitcnt vmcnt(0)" ::: "memory");
        }
        SCHED0(); SBAR(); SCHED0();
        __builtin_amdgcn_s_setprio(1);
        #pragma unroll
        for (int kk = 0; kk < 2; ++kk) {
            int slotX = ((kk * 4 + hi) ^ (lo & 7)) << 3;
            bf16x8 a0 = *(const bf16x8*)(&sA[buf][(wm * 32 +      lo) * 64 + slotX]);
            bf16x8 a1 = *(const bf16x8*)(&sA[buf][(wm * 32 + 16 + lo) * 64 + slotX]);
            #pragma unroll
            for (int n = 0; n < 4; ++n) {
                bf16x8 bb = *(const bf16x8*)(&sB[buf][(wn * 64 + n * 16 + lo) * 64 + slotX]);
                if (left) {
                    acc[0][n] = MFMA(a0, bb, acc[0][n]);
                    acc[1][n] = MFMA(a1, bb, acc[1][n]);
                } else {
                    acc[0][n] = MFMA(bb, a0, acc[0][n]);
                    acc[1][n] = MFMA(bb, a1, acc[1][n]);
                }
            }
        }
        __builtin_amdgcn_s_setprio(0);
        if (t < 7) { SCHED0(); SBAR(); SCHED0(); }
    }
#undef G1_STAGE

    int ksoff = blockIdx.z * 262144;
    if (left) {
        #pragma unroll
        for (int m = 0; m < 2; ++m) {
            int ib = i0 + wm * 32 + m * 16 + hi * 4;
            #pragma unroll
            for (int n = 0; n < 4; ++n) {
                int j = j0 + wn * 64 + n * 16 + lo;
                #pragma unroll
                for (int r = 0; r < 4; ++r)
                    CpL[ksoff + (ib + r) * 512 + j] = acc[m][n][r];
            }
        }
    } else {
        #pragma unroll
        for (int m = 0; m < 2; ++m) {
            int ic = i0 + wm * 32 + m * 16 + lo;
            #pragma unroll
            for (int n = 0; n < 4; ++n) {
                int db = j0 - 512 + wn * 64 + n * 16 + hi * 4;
                #pragma unroll
                for (int r = 0; r < 4; ++r)
                    CpR[ksoff + (db + r) * 512 + ic] = acc[m][n][r];
            }
        }
    }
}

// ---------------- k_mid: sum 8 split-K partials -> bf16 (M1bf + M2t) ----------------
__global__ void k_mid(const float* __restrict__ CpL, const float* __restrict__ CpR,
                      unsigned short* __restrict__ M1bf, unsigned short* __restrict__ M2t) {
    int bx = blockIdx.x;
    const float* Cp = (bx < 256) ? CpL : CpR;
    unsigned short* ob = (bx < 256) ? M1bf : M2t;
    int gid = (bx & 255) * 256 + threadIdx.x;
    float4 s = ((const float4*)Cp)[gid];
    #pragma unroll
    for (int ks = 1; ks < 8; ++ks) {
        float4 t = ((const float4*)Cp)[ks * 65536 + gid];
        s.x += t.x; s.y += t.y; s.z += t.z; s.w += t.w;
    }
    ushort4 o;
    o.x = f2bf(s.x); o.y = f2bf(s.y); o.z = f2bf(s.z); o.w = f2bf(s.w);
    ((ushort4*)ob)[gid] = o;
}

// cb[b][i] = (1/T) * sum_d sumx[b][d]*M2t[d][i] + bias2[i] + m1b[i]
__global__ void k_cb(const float* __restrict__ sumxp, const unsigned short* __restrict__ M2t,
                     const float* __restrict__ bias2, const float* __restrict__ m1b,
                     float* __restrict__ cbo) {
    int b = blockIdx.x, i0 = blockIdx.y * 64;
    int tid = threadIdx.x;
    __shared__ float sSx[512];
    for (int d = tid; d < 512; d += 256) {
        float s = 0.f;
        #pragma unroll
        for (int p = 0; p < 16; ++p)
            s += sumxp[(size_t)(b * 16 + p) * 512 + d];
        sSx[d] = s;
    }
    __syncthreads();
    int il = tid & 63, dq = tid >> 6;
    const unsigned short* mp = M2t + (size_t)dq * 128 * 512 + i0 + il;
    float acc = 0.f;
    #pragma unroll 4
    for (int dd = 0; dd < 128; ++dd)
        acc += sSx[dq * 128 + dd] * bf2f(mp[(size_t)dd * 512]);
    __shared__ float sPart[4][64];
    sPart[dq][il] = acc;
    __syncthreads();
    if (tid < 64) {
        float v = sPart[0][tid] + sPart[1][tid] + sPart[2][tid] + sPart[3][tid];
        cbo[b * 512 + i0 + tid] = v * (1.0f / 1024.0f) + bias2[i0 + tid] + m1b[i0 + tid];
    }
}

// ---------------- GEMM2 (K-loop only), 32-row tiles, 512 blocks x 256 thr, 2 blocks/CU ----
__launch_bounds__(256, 2)
__global__ void k_gemm2s(const float* __restrict__ x,
                         const unsigned short* __restrict__ M1bf,
                         unsigned short* __restrict__ ypk) {
    __shared__ __align__(16) unsigned short sA[32 * 64];    // 4 KB
    __shared__ __align__(16) unsigned short sB[512 * 64];   // 64 KB
    int bt0 = blockIdx.x * 32;
    int tid = threadIdx.x, lane = tid & 63, w = tid >> 6;   // 4 waves
    int lo = lane & 15, hi = lane >> 4;
    int lr = lane >> 3, sl = lane & 7;
    int arow = tid >> 3, aslot = tid & 7;                    // 32 rows x 8 slots
    const float* gA = x + (size_t)(bt0 + arow) * 512 + aslot * 8;
    unsigned short* dAp = sA + arow * 64 + ((aslot ^ (arow & 7)) << 3);
    const unsigned short* gB[16];
    #pragma unroll
    for (int g = 0; g < 16; ++g)
        gB[g] = M1bf + (size_t)(w * 128 + g * 8 + lr) * 512 + ((sl ^ lr) << 3);
    f32x4 acc[2][8] = {};
    for (int k0 = 0; k0 < 512; k0 += 64) {
        if (k0) __syncthreads();
        #pragma unroll
        for (int g = 0; g < 16; ++g)
            GLOAD_LDS16(gB[g] + k0, &sB[(w * 128 + g * 8) * 64]);
        float4 f0 = *(const float4*)(gA + k0);
        float4 f1 = *(const float4*)(gA + k0 + 4);
        bf16x8 pk;
        pk[0] = (short)f2bf(f0.x); pk[1] = (short)f2bf(f0.y);
        pk[2] = (short)f2bf(f0.z); pk[3] = (short)f2bf(f0.w);
        pk[4] = (short)f2bf(f1.x); pk[5] = (short)f2bf(f1.y);
        pk[6] = (short)f2bf(f1.z); pk[7] = (short)f2bf(f1.w);
        *(bf16x8*)dAp = pk;
        __syncthreads();
        #pragma unroll
        for (int kk = 0; kk < 2; ++kk) {
            int slotX = ((kk * 4 + hi) ^ (lo & 7)) << 3;
            bf16x8 a0 = *(const bf16x8*)(sA + (     lo) * 64 + slotX);
            bf16x8 a1 = *(const bf16x8*)(sA + (16 + lo) * 64 + slotX);
            #pragma unroll
            for (int n = 0; n < 8; ++n) {
                bf16x8 bb = *(const bf16x8*)(sB + (w * 128 + n * 16 + lo) * 64 + slotX);
                acc[0][n] = MFMA(a0, bb, acc[0][n]);
                acc[1][n] = MFMA(a1, bb, acc[1][n]);
            }
        }
    }
    unsigned short* yb = ypk + (size_t)blockIdx.x * 16384;
    #pragma unroll
    for (int m = 0; m < 2; ++m) {
        #pragma unroll
        for (int n = 0; n < 8; ++n) {
            unsigned int u0 = pk2(acc[m][n][0], acc[m][n][1]);
            unsigned int u1 = pk2(acc[m][n][2], acc[m][n][3]);
            uint2 o; o.x = u0; o.y = u1;
            *(uint2*)(yb + ((((w * 2 + m) * 8 + n) << 8) + (lane << 2))) = o;
        }
    }
}

// ---------------- LN + tanh + logit (32-row blocks, 512 x 256 thr) ----------------
__launch_bounds__(256)
__global__ void k_lnlogit(const unsigned short* __restrict__ ypk,
                          const float* __restrict__ cb,
                          const float* __restrict__ lng, const float* __restrict__ lnb,
                          const float* __restrict__ m2w, const float* __restrict__ m2b,
                          float* __restrict__ logits) {
    __shared__ __align__(16) unsigned short sY[16384];   // 32 KB
    __shared__ float sCb[512], sG[512], sBe[512], sW[512];
    __shared__ float sS1[32][8], sS2[32][8], sLg[32][8];
    int blk = blockIdx.x;
    int bt0 = blk * 32;
    int b = bt0 >> 10;
    int tid = threadIdx.x, w = tid >> 6, lane = tid & 63;
    #pragma unroll
    for (int q = 0; q < 2; ++q) {
        int c = q * 256 + tid;
        sCb[c] = cb[b * 512 + c];
        sG[c]  = lng[c];
        sBe[c] = lnb[c];
        sW[c]  = m2w[c];
    }
    const unsigned short* src = ypk + (size_t)blk * 16384;
    #pragma unroll
    for (int it = 0; it < 8; ++it) {
        int off = (w * 8 + it) * 512;           // 4 waves x 8 iters x 1KB = 32KB
        GLOAD_LDS16(src + off + (lane << 3), &sY[off]);
    }
    asm volatile("s_waitcnt vmcnt(0)" ::: "memory");
    __syncthreads();

    int row = tid >> 3, sub = tid & 7;           // 32 rows x 8 col-groups
    int m = row >> 4, hi = (row >> 2) & 3, r = row & 3;
    float s1 = 0.f, s2 = 0.f;
    #pragma unroll
    for (int wn = 0; wn < 4; ++wn) {
        #pragma unroll
        for (int n = 0; n < 8; ++n) {
            int c = (wn * 2 + m) * 8 + n;
            int eb = c * 256 + r;
            int ib = wn * 128 + n * 16;
            #pragma unroll
            for (int l2 = 0; l2 < 2; ++l2) {
                int lo = sub * 2 + l2;
                float v = bf2f(sY[eb + (hi * 16 + lo) * 4]) + sCb[ib + lo];
                s1 += v; s2 += v * v;
            }
        }
    }
    sS1[row][sub] = s1; sS2[row][sub] = s2;
    __syncthreads();
    float a1 = 0.f, a2 = 0.f;
    #pragma unroll
    for (int q = 0; q < 8; ++q) { a1 += sS1[row][q]; a2 += sS2[row][q]; }
    float mu = a1 * (1.0f / 512.0f);
    float var = a2 * (1.0f / 512.0f) - mu * mu;
    float rs = rsqrtf(var + 1e-5f);
    float lg = 0.f;
    #pragma unroll
    for (int wn = 0; wn < 4; ++wn) {
        #pragma unroll
        for (int n = 0; n < 8; ++n) {
            int c = (wn * 2 + m) * 8 + n;
            int eb = c * 256 + r;
            int ib = wn * 128 + n * 16;
            #pragma unroll
            for (int l2 = 0; l2 < 2; ++l2) {
                int lo = sub * 2 + l2;
                float v = bf2f(sY[eb + (hi * 16 + lo) * 4]) + sCb[ib + lo];
                float h = tanh_fast((v - mu) * rs * sG[ib + lo] + sBe[ib + lo]);
                lg += h * sW[ib + lo];
            }
        }
    }
    sLg[row][sub] = lg;
    __syncthreads();
    if (sub == 0) {
        float t = 0.f;
        #pragma unroll
        for (int q = 0; q < 8; ++q) t += sLg[row][q];
        logits[bt0 + row] = t + m2b[0];
    }
}

// ---------------- softmax (per-block recompute) + context partials ----------------
__global__ void k_swctx(const float* __restrict__ x, const float* __restrict__ logits,
                        float* __restrict__ ctxp, float* __restrict__ attn) {
    int b = blockIdx.x, tc = blockIdx.y;
    int tid = threadIdx.x;
    __shared__ float red[4];
    __shared__ float sWt[1024];
    float4 v = ((const float4*)(logits + b * 1024))[tid];
    float mx = fmaxf(fmaxf(v.x, v.y), fmaxf(v.z, v.w));
    for (int off = 32; off; off >>= 1) mx = fmaxf(mx, __shfl_xor(mx, off));
    if ((tid & 63) == 0) red[tid >> 6] = mx;
    __syncthreads();
    mx = fmaxf(fmaxf(red[0], red[1]), fmaxf(red[2], red[3]));
    float e0 = expf(v.x - mx), e1 = expf(v.y - mx), e2 = expf(v.z - mx), e3 = expf(v.w - mx);
    float sm = e0 + e1 + e2 + e3;
    for (int off = 32; off; off >>= 1) sm += __shfl_xor(sm, off);
    __syncthreads();
    if ((tid & 63) == 0) red[tid >> 6] = sm;
    __syncthreads();
    float inv = 1.0f / (red[0] + red[1] + red[2] + red[3]);
    float4 o; o.x = e0 * inv; o.y = e1 * inv; o.z = e2 * inv; o.w = e3 * inv;
    ((float4*)sWt)[tid] = o;
    if (tc == 0) ((float4*)(attn + b * 1024))[tid] = o;
    __syncthreads();
    const float* xp = x + ((size_t)b * 1024 + tc * 64) * 512;
    const float* wp = sWt + tc * 64;
    float a0 = 0.f, a1 = 0.f;
    for (int t = 0; t < 64; ++t) {
        float wv = wp[t];
        a0 += wv * xp[(size_t)t * 512 + tid];
        a1 += wv * xp[(size_t)t * 512 + tid + 256];
    }
    float* op = ctxp + (size_t)(b * 16 + tc) * 512;
    op[tid] = a0;
    op[tid + 256] = a1;
}

// context[b][d] = sum of 16 partials
__global__ void k_ctxred(const float* __restrict__ ctxp, float* __restrict__ ctx) {
    int idx = blockIdx.x * 256 + threadIdx.x;   // 8192
    int b = idx >> 9, d = idx & 511;
    float s = 0.f;
    #pragma unroll
    for (int p = 0; p < 16; ++p)
        s += ctxp[(size_t)(b * 16 + p) * 512 + d];
    ctx[b * 512 + d] = s;
}

// ---------------- launch ----------------
extern "C" void kernel_launch(void* const* d_in, const int* in_sizes, int n_in,
                              void* d_out, int out_size, void* d_ws, size_t ws_size,
                              hipStream_t stream) {
    (void)in_sizes; (void)n_in; (void)out_size; (void)ws_size;
    const float* x    = (const float*)d_in[0];
    const float* Went = (const float*)d_in[1];
    const float* bent = (const float*)d_in[2];
    const float* m1w  = (const float*)d_in[3];
    const float* m1b  = (const float*)d_in[4];
    const float* lng  = (const float*)d_in[5];
    const float* lnb  = (const float*)d_in[6];
    const float* m2w  = (const float*)d_in[7];
    const float* m2b  = (const float*)d_in[8];
    float* out = (float*)d_out;            // [0,8192): context ; [8192,24576): attn
    char* ws = (char*)d_ws;

    unsigned short* Abf   = (unsigned short*)(ws);                        // 4 MB
    unsigned short* WT    = (unsigned short*)(ws + 4194304);              // 8 MB
    float* CpL            = (float*)(ws + 12582912);                      // 8 MB
    float* CpR            = (float*)(ws + 20971520);                      // 8 MB
    unsigned short* ypk   = (unsigned short*)(ws + 12582912);             // 16 MB (reuses CpL/CpR after k_mid)
    unsigned short* M1bf  = (unsigned short*)(ws + 29360128);             // 512 KB
    unsigned short* M2t   = (unsigned short*)(ws + 29884416);             // 512 KB
    float* sumxp  = (float*)(ws + 30408704);                              // 512 KB
    float* ctxp   = (float*)(ws + 30932992);                              // 512 KB
    float* bias2  = (float*)(ws + 31457280);                              // 2 KB
    float* cb     = (float*)(ws + 31459328);                              // 32 KB
    float* logits = (float*)(ws + 31492096);                              // 64 KB

    k_pre<<<1792, 256, 0, stream>>>(x, m1w, bent, Went, sumxp, Abf, bias2, WT);
    k_gemm1<<<dim3(8, 4, 8), 512, 0, stream>>>(Abf, WT, CpL, CpR);
    k_mid<<<512, 256, 0, stream>>>(CpL, CpR, M1bf, M2t);
    k_cb<<<dim3(16, 8), 256, 0, stream>>>(sumxp, M2t, bias2, m1b, cb);
    k_gemm2s<<<512, 256, 0, stream>>>(x, M1bf, ypk);
    k_lnlogit<<<512, 256, 0, stream>>>(ypk, cb, lng, lnb, m2w, m2b, logits);
    k_swctx<<<dim3(16, 16), 256, 0, stream>>>(x, logits, ctxp, out + 8192);
    k_ctxred<<<32, 256, 0, stream>>>(ctxp, out);
}

// Round 12
// 87.707 us; speedup vs baseline: 1.6429x; 1.0056x over previous
//
#include <hip/hip_runtime.h>
#include <hip/hip_bf16.h>

typedef __attribute__((ext_vector_type(8))) short bf16x8;
typedef __attribute__((ext_vector_type(4))) float f32x4;

__device__ __forceinline__ float bf2f(unsigned short u) {
    union { unsigned int i; float f; } c; c.i = ((unsigned int)u) << 16; return c.f;
}
__device__ __forceinline__ unsigned short f2bf(float f) {
    union { float f; unsigned int i; } c; c.f = f;
    unsigned int x = c.i;
    x += 0x7fffu + ((x >> 16) & 1u);   // round-to-nearest-even
    return (unsigned short)(x >> 16);
}
// pack two f32 -> u32 of 2 bf16 (RNE), elem0 in low half
__device__ __forceinline__ unsigned int pk2(float a, float b) {
    __hip_bfloat162 h = __float22bfloat162_rn(float2{a, b});
    union { __hip_bfloat162 h; unsigned int u; } c; c.h = h; return c.u;
}
__device__ __forceinline__ float tanh_fast(float v) {
    float a = fabsf(v);
    a = fminf(a, 15.0f);
    float e = __expf(2.0f * a);
    float t = 1.0f - 2.0f / (e + 1.0f);
    return copysignf(t, v);
}

// async global->LDS, 16B per lane; lptr must be wave-uniform, gptr per-lane
#define GLOAD_LDS16(gp, lp) \
    __builtin_amdgcn_global_load_lds((const __attribute__((address_space(1))) void*)(gp), \
                                     (__attribute__((address_space(3))) void*)(lp), 16, 0, 0)

#define MFMA(a, b, c) __builtin_amdgcn_mfma_f32_16x16x32_bf16((a), (b), (c), 0, 0, 0)

#define SBAR()  __builtin_amdgcn_s_barrier()
#define SCHED0() __builtin_amdgcn_sched_barrier(0)

// ---------------- k_pre: fused {sumxp | prepA | conv_W} ----------------
__global__ void k_pre(const float* __restrict__ x, const float* __restrict__ m1w,
                      const float* __restrict__ bent, const float* __restrict__ W,
                      float* __restrict__ sumxp, unsigned short* __restrict__ Abf,
                      float* __restrict__ bias2, unsigned short* __restrict__ WT) {
    __shared__ float tile[128][33];
    __shared__ float r4[4];
    int bid = blockIdx.x;
    int tid = threadIdx.x;
    if (bid < 256) {
        int b = bid >> 4, tc = bid & 15;
        const float* xp = x + ((size_t)b * 1024 + tc * 64) * 512;
        float a0 = 0.f, a1 = 0.f;
        for (int t = 0; t < 64; ++t) {
            a0 += xp[(size_t)t * 512 + tid];
            a1 += xp[(size_t)t * 512 + tid + 256];
        }
        float* o = sumxp + (size_t)(b * 16 + tc) * 512;
        o[tid] = a0;
        o[tid + 256] = a1;
    } else if (bid < 768) {
        int i = bid - 256;
        const float* row = m1w + (size_t)i * 4096;
        float acc = 0.f;
        #pragma unroll
        for (int q = 0; q < 4; ++q) {
            int col = q * 1024 + tid * 4;
            float4 v = *(const float4*)(row + col);
            ushort4 o;
            o.x = f2bf(v.x); o.y = f2bf(v.y); o.z = f2bf(v.z); o.w = f2bf(v.w);
            *(ushort4*)(Abf + (size_t)i * 4096 + col) = o;
            int e0 = col >> 3, s0 = col & 7;
            acc += v.x * bent[(s0    ) * 512 + e0];
            acc += v.y * bent[(s0 + 1) * 512 + e0];
            acc += v.z * bent[(s0 + 2) * 512 + e0];
            acc += v.w * bent[(s0 + 3) * 512 + e0];
        }
        #pragma unroll
        for (int off = 32; off; off >>= 1) acc += __shfl_xor(acc, off);
        if ((tid & 63) == 0) r4[tid >> 6] = acc;
        __syncthreads();
        if (tid == 0) bias2[i] = r4[0] + r4[1] + r4[2] + r4[3];
    } else {
        int idx = bid - 768;
        int e0 = (idx & 31) * 16;
        int j0 = (idx >> 5) * 32;
        int tx = tid & 31, ty = tid >> 5;
        #pragma unroll
        for (int q = 0; q < 16; ++q) {
            int lk = q * 8 + ty;
            int de = lk >> 3, s = lk & 7;
            int r = s * 512 + e0 + de;
            tile[lk][tx] = W[(size_t)r * 1024 + j0 + tx];
        }
        __syncthreads();
        int j = tid >> 3, ck = (tid & 7) * 16;
        unsigned short* dst = WT + (size_t)(j0 + j) * 4096 + e0 * 8 + ck;
        #pragma unroll
        for (int g = 0; g < 4; ++g) {
            ushort4 o;
            o.x = f2bf(tile[ck + g * 4 + 0][j]);
            o.y = f2bf(tile[ck + g * 4 + 1][j]);
            o.z = f2bf(tile[ck + g * 4 + 2][j]);
            o.w = f2bf(tile[ck + g * 4 + 3][j]);
            *(ushort4*)(dst + g * 4) = o;
        }
    }
}

// ---------------- GEMM1 (split-K=8, pipelined): C[i,j] = sum_k Abf[i,k] WT[j,k] ----------------
__launch_bounds__(512, 2)
__global__ void k_gemm1(const unsigned short* __restrict__ Abf,
                        const unsigned short* __restrict__ WT,
                        float* __restrict__ CpL, float* __restrict__ CpR) {
    __shared__ __align__(16) unsigned short sA[2][64 * 64];
    __shared__ __align__(16) unsigned short sB[2][256 * 64];
    int i0 = blockIdx.x * 64;
    int j0 = blockIdx.y * 256;
    int kbase = blockIdx.z * 512;
    int tid = threadIdx.x, lane = tid & 63, w = tid >> 6;
    int wm = w >> 2, wn = w & 3;
    int lr = lane >> 3, sl = lane & 7;
    int lo = lane & 15, hi = lane >> 4;
    int arow = w * 8 + lr;
    const unsigned short* gA = Abf + (size_t)(i0 + arow) * 4096 + kbase + ((sl ^ lr) << 3);
    const unsigned short* gB0 = WT + (size_t)(j0 + w * 32 + 0 * 8 + lr) * 4096 + kbase + ((sl ^ lr) << 3);
    const unsigned short* gB1 = WT + (size_t)(j0 + w * 32 + 1 * 8 + lr) * 4096 + kbase + ((sl ^ lr) << 3);
    const unsigned short* gB2 = WT + (size_t)(j0 + w * 32 + 2 * 8 + lr) * 4096 + kbase + ((sl ^ lr) << 3);
    const unsigned short* gB3 = WT + (size_t)(j0 + w * 32 + 3 * 8 + lr) * 4096 + kbase + ((sl ^ lr) << 3);
    bool left = (blockIdx.y < 2);
    f32x4 acc[2][4] = {};

#define G1_STAGE(tt, bufn)                                                    \
    do {                                                                      \
        int koff = (tt) * 64;                                                 \
        GLOAD_LDS16(gA + koff, &sA[bufn][w * 8 * 64]);                        \
        GLOAD_LDS16(gB0 + koff, &sB[bufn][(w * 32 + 0) * 64]);                \
        GLOAD_LDS16(gB1 + koff, &sB[bufn][(w * 32 + 8) * 64]);                \
        GLOAD_LDS16(gB2 + koff, &sB[bufn][(w * 32 + 16) * 64]);               \
        GLOAD_LDS16(gB3 + koff, &sB[bufn][(w * 32 + 24) * 64]);               \
        SCHED0();                                                             \
    } while (0)

    G1_STAGE(0, 0);
    #pragma unroll
    for (int t = 0; t < 8; ++t) {
        int buf = t & 1;
        if (t < 7) {
            G1_STAGE(t + 1, buf ^ 1);
            asm volatile("s_waitcnt vmcnt(5)" ::: "memory");
        } else {
            asm volatile("s_waitcnt vmcnt(0)" ::: "memory");
        }
        SCHED0(); SBAR(); SCHED0();
        __builtin_amdgcn_s_setprio(1);
        #pragma unroll
        for (int kk = 0; kk < 2; ++kk) {
            int slotX = ((kk * 4 + hi) ^ (lo & 7)) << 3;
            bf16x8 a0 = *(const bf16x8*)(&sA[buf][(wm * 32 +      lo) * 64 + slotX]);
            bf16x8 a1 = *(const bf16x8*)(&sA[buf][(wm * 32 + 16 + lo) * 64 + slotX]);
            #pragma unroll
            for (int n = 0; n < 4; ++n) {
                bf16x8 bb = *(const bf16x8*)(&sB[buf][(wn * 64 + n * 16 + lo) * 64 + slotX]);
                if (left) {
                    acc[0][n] = MFMA(a0, bb, acc[0][n]);
                    acc[1][n] = MFMA(a1, bb, acc[1][n]);
                } else {
                    acc[0][n] = MFMA(bb, a0, acc[0][n]);
                    acc[1][n] = MFMA(bb, a1, acc[1][n]);
                }
            }
        }
        __builtin_amdgcn_s_setprio(0);
        if (t < 7) { SCHED0(); SBAR(); SCHED0(); }
    }
#undef G1_STAGE

    int ksoff = blockIdx.z * 262144;
    if (left) {
        #pragma unroll
        for (int m = 0; m < 2; ++m) {
            int ib = i0 + wm * 32 + m * 16 + hi * 4;
            #pragma unroll
            for (int n = 0; n < 4; ++n) {
                int j = j0 + wn * 64 + n * 16 + lo;
                #pragma unroll
                for (int r = 0; r < 4; ++r)
                    CpL[ksoff + (ib + r) * 512 + j] = acc[m][n][r];
            }
        }
    } else {
        #pragma unroll
        for (int m = 0; m < 2; ++m) {
            int ic = i0 + wm * 32 + m * 16 + lo;
            #pragma unroll
            for (int n = 0; n < 4; ++n) {
                int db = j0 - 512 + wn * 64 + n * 16 + hi * 4;
                #pragma unroll
                for (int r = 0; r < 4; ++r)
                    CpR[ksoff + (db + r) * 512 + ic] = acc[m][n][r];
            }
        }
    }
}

// ---------------- k_mid: sum 8 split-K partials -> bf16 (M1bf + M2t) ----------------
__global__ void k_mid(const float* __restrict__ CpL, const float* __restrict__ CpR,
                      unsigned short* __restrict__ M1bf, unsigned short* __restrict__ M2t) {
    int bx = blockIdx.x;
    const float* Cp = (bx < 256) ? CpL : CpR;
    unsigned short* ob = (bx < 256) ? M1bf : M2t;
    int gid = (bx & 255) * 256 + threadIdx.x;
    float4 s = ((const float4*)Cp)[gid];
    #pragma unroll
    for (int ks = 1; ks < 8; ++ks) {
        float4 t = ((const float4*)Cp)[ks * 65536 + gid];
        s.x += t.x; s.y += t.y; s.z += t.z; s.w += t.w;
    }
    ushort4 o;
    o.x = f2bf(s.x); o.y = f2bf(s.y); o.z = f2bf(s.z); o.w = f2bf(s.w);
    ((ushort4*)ob)[gid] = o;
}

// cb[b][i] = (1/T) * sum_d sumx[b][d]*M2t[d][i] + bias2[i] + m1b[i]
__global__ void k_cb(const float* __restrict__ sumxp, const unsigned short* __restrict__ M2t,
                     const float* __restrict__ bias2, const float* __restrict__ m1b,
                     float* __restrict__ cbo) {
    int b = blockIdx.x, i0 = blockIdx.y * 64;
    int tid = threadIdx.x;
    __shared__ float sSx[512];
    for (int d = tid; d < 512; d += 256) {
        float s = 0.f;
        #pragma unroll
        for (int p = 0; p < 16; ++p)
            s += sumxp[(size_t)(b * 16 + p) * 512 + d];
        sSx[d] = s;
    }
    __syncthreads();
    int il = tid & 63, dq = tid >> 6;
    const unsigned short* mp = M2t + (size_t)dq * 128 * 512 + i0 + il;
    float acc = 0.f;
    #pragma unroll 4
    for (int dd = 0; dd < 128; ++dd)
        acc += sSx[dq * 128 + dd] * bf2f(mp[(size_t)dd * 512]);
    __shared__ float sPart[4][64];
    sPart[dq][il] = acc;
    __syncthreads();
    if (tid < 64) {
        float v = sPart[0][tid] + sPart[1][tid] + sPart[2][tid] + sPart[3][tid];
        cbo[b * 512 + i0 + tid] = v * (1.0f / 1024.0f) + bias2[i0 + tid] + m1b[i0 + tid];
    }
}

// ---------------- GEMM2 (K-loop only), 32 rows x 256 cols, grid (512,2), 16 waves/CU ----
// y[bt, jb*256+c] = sum_d x[bt,d]*M1[jb*256+c,d]
// ypk block (jb*512+bx): chunk c = (w*2+m)*4+n (256 elems), elem (hi*16+lo)*4+r
//   -> row bt0 + m*16 + hi*4 + r, col jb*256 + w*64 + n*16 + lo
__launch_bounds__(256, 4)
__global__ void k_gemm2s(const float* __restrict__ x,
                         const unsigned short* __restrict__ M1bf,
                         unsigned short* __restrict__ ypk) {
    __shared__ __align__(16) unsigned short sA[32 * 64];    // 4 KB
    __shared__ __align__(16) unsigned short sB[256 * 64];   // 32 KB
    int bt0 = blockIdx.x * 32;
    int jb  = blockIdx.y;                                    // col half
    int tid = threadIdx.x, lane = tid & 63, w = tid >> 6;    // 4 waves
    int lo = lane & 15, hi = lane >> 4;
    int lr = lane >> 3, sl = lane & 7;
    int arow = tid >> 3, aslot = tid & 7;                    // 32 rows x 8 slots
    const float* gA = x + (size_t)(bt0 + arow) * 512 + aslot * 8;
    unsigned short* dAp = sA + arow * 64 + ((aslot ^ (arow & 7)) << 3);
    const unsigned short* gB[8];
    #pragma unroll
    for (int g = 0; g < 8; ++g)
        gB[g] = M1bf + (size_t)(jb * 256 + w * 64 + g * 8 + lr) * 512 + ((sl ^ lr) << 3);
    f32x4 acc[2][4] = {};
    for (int k0 = 0; k0 < 512; k0 += 64) {
        if (k0) __syncthreads();
        #pragma unroll
        for (int g = 0; g < 8; ++g)
            GLOAD_LDS16(gB[g] + k0, &sB[(w * 64 + g * 8) * 64]);
        float4 f0 = *(const float4*)(gA + k0);
        float4 f1 = *(const float4*)(gA + k0 + 4);
        bf16x8 pk;
        pk[0] = (short)f2bf(f0.x); pk[1] = (short)f2bf(f0.y);
        pk[2] = (short)f2bf(f0.z); pk[3] = (short)f2bf(f0.w);
        pk[4] = (short)f2bf(f1.x); pk[5] = (short)f2bf(f1.y);
        pk[6] = (short)f2bf(f1.z); pk[7] = (short)f2bf(f1.w);
        *(bf16x8*)dAp = pk;
        __syncthreads();
        #pragma unroll
        for (int kk = 0; kk < 2; ++kk) {
            int slotX = ((kk * 4 + hi) ^ (lo & 7)) << 3;
            bf16x8 a0 = *(const bf16x8*)(sA + (     lo) * 64 + slotX);
            bf16x8 a1 = *(const bf16x8*)(sA + (16 + lo) * 64 + slotX);
            #pragma unroll
            for (int n = 0; n < 4; ++n) {
                bf16x8 bb = *(const bf16x8*)(sB + (w * 64 + n * 16 + lo) * 64 + slotX);
                acc[0][n] = MFMA(a0, bb, acc[0][n]);
                acc[1][n] = MFMA(a1, bb, acc[1][n]);
            }
        }
    }
    unsigned short* yb = ypk + (size_t)(jb * 512 + blockIdx.x) * 8192;
    #pragma unroll
    for (int m = 0; m < 2; ++m) {
        #pragma unroll
        for (int n = 0; n < 4; ++n) {
            unsigned int u0 = pk2(acc[m][n][0], acc[m][n][1]);
            unsigned int u1 = pk2(acc[m][n][2], acc[m][n][3]);
            uint2 o; o.x = u0; o.y = u1;
            *(uint2*)(yb + ((((w * 2 + m) * 4 + n) << 8) + (lane << 2))) = o;
        }
    }
}

// ---------------- LN + tanh + logit (32-row blocks; reads both col-halves of ypk) ----
__launch_bounds__(256)
__global__ void k_lnlogit(const unsigned short* __restrict__ ypk,
                          const float* __restrict__ cb,
                          const float* __restrict__ lng, const float* __restrict__ lnb,
                          const float* __restrict__ m2w, const float* __restrict__ m2b,
                          float* __restrict__ logits) {
    __shared__ __align__(16) unsigned short sY[16384];   // 32 KB: [by][c][256]
    __shared__ float sCb[512], sG[512], sBe[512], sW[512];
    __shared__ float sS1[32][8], sS2[32][8], sLg[32][8];
    int blk = blockIdx.x;
    int bt0 = blk * 32;
    int b = bt0 >> 10;
    int tid = threadIdx.x, w = tid >> 6, lane = tid & 63;
    #pragma unroll
    for (int q = 0; q < 2; ++q) {
        int c = q * 256 + tid;
        sCb[c] = cb[b * 512 + c];
        sG[c]  = lng[c];
        sBe[c] = lnb[c];
        sW[c]  = m2w[c];
    }
    const unsigned short* s0 = ypk + (size_t)blk * 8192;            // jb=0 half
    const unsigned short* s1 = ypk + (size_t)(512 + blk) * 8192;    // jb=1 half
    #pragma unroll
    for (int it = 0; it < 8; ++it) {
        int off = (w * 8 + it) * 512;           // 16 rounds x 1KB = 32KB
        const unsigned short* src = (off < 8192) ? (s0 + off) : (s1 + off - 8192);
        GLOAD_LDS16(src + (lane << 3), &sY[off]);
    }
    asm volatile("s_waitcnt vmcnt(0)" ::: "memory");
    __syncthreads();

    int row = tid >> 3, sub = tid & 7;           // 32 rows x 8 col-groups
    int m = row >> 4, hi = (row >> 2) & 3, r = row & 3;
    float s1v = 0.f, s2v = 0.f;
    #pragma unroll
    for (int by = 0; by < 2; ++by) {
        #pragma unroll
        for (int ww = 0; ww < 4; ++ww) {
            #pragma unroll
            for (int n = 0; n < 4; ++n) {
                int c = (ww * 2 + m) * 4 + n;
                int eb = by * 8192 + c * 256 + r;
                int ib = by * 256 + ww * 64 + n * 16;
                #pragma unroll
                for (int l2 = 0; l2 < 2; ++l2) {
                    int lo = sub * 2 + l2;
                    float v = bf2f(sY[eb + (hi * 16 + lo) * 4]) + sCb[ib + lo];
                    s1v += v; s2v += v * v;
                }
            }
        }
    }
    sS1[row][sub] = s1v; sS2[row][sub] = s2v;
    __syncthreads();
    float a1 = 0.f, a2 = 0.f;
    #pragma unroll
    for (int q = 0; q < 8; ++q) { a1 += sS1[row][q]; a2 += sS2[row][q]; }
    float mu = a1 * (1.0f / 512.0f);
    float var = a2 * (1.0f / 512.0f) - mu * mu;
    float rs = rsqrtf(var + 1e-5f);
    float lg = 0.f;
    #pragma unroll
    for (int by = 0; by < 2; ++by) {
        #pragma unroll
        for (int ww = 0; ww < 4; ++ww) {
            #pragma unroll
            for (int n = 0; n < 4; ++n) {
                int c = (ww * 2 + m) * 4 + n;
                int eb = by * 8192 + c * 256 + r;
                int ib = by * 256 + ww * 64 + n * 16;
                #pragma unroll
                for (int l2 = 0; l2 < 2; ++l2) {
                    int lo = sub * 2 + l2;
                    float v = bf2f(sY[eb + (hi * 16 + lo) * 4]) + sCb[ib + lo];
                    float h = tanh_fast((v - mu) * rs * sG[ib + lo] + sBe[ib + lo]);
                    lg += h * sW[ib + lo];
                }
            }
        }
    }
    sLg[row][sub] = lg;
    __syncthreads();
    if (sub == 0) {
        float t = 0.f;
        #pragma unroll
        for (int q = 0; q < 8; ++q) t += sLg[row][q];
        logits[bt0 + row] = t + m2b[0];
    }
}

// ---------------- softmax (per-block recompute) + context partials ----------------
__global__ void k_swctx(const float* __restrict__ x, const float* __restrict__ logits,
                        float* __restrict__ ctxp, float* __restrict__ attn) {
    int b = blockIdx.x, tc = blockIdx.y;
    int tid = threadIdx.x;
    __shared__ float red[4];
    __shared__ float sWt[1024];
    float4 v = ((const float4*)(logits + b * 1024))[tid];
    float mx = fmaxf(fmaxf(v.x, v.y), fmaxf(v.z, v.w));
    for (int off = 32; off; off >>= 1) mx = fmaxf(mx, __shfl_xor(mx, off));
    if ((tid & 63) == 0) red[tid >> 6] = mx;
    __syncthreads();
    mx = fmaxf(fmaxf(red[0], red[1]), fmaxf(red[2], red[3]));
    float e0 = expf(v.x - mx), e1 = expf(v.y - mx), e2 = expf(v.z - mx), e3 = expf(v.w - mx);
    float sm = e0 + e1 + e2 + e3;
    for (int off = 32; off; off >>= 1) sm += __shfl_xor(sm, off);
    __syncthreads();
    if ((tid & 63) == 0) red[tid >> 6] = sm;
    __syncthreads();
    float inv = 1.0f / (red[0] + red[1] + red[2] + red[3]);
    float4 o; o.x = e0 * inv; o.y = e1 * inv; o.z = e2 * inv; o.w = e3 * inv;
    ((float4*)sWt)[tid] = o;
    if (tc == 0) ((float4*)(attn + b * 1024))[tid] = o;
    __syncthreads();
    const float* xp = x + ((size_t)b * 1024 + tc * 64) * 512;
    const float* wp = sWt + tc * 64;
    float a0 = 0.f, a1 = 0.f;
    for (int t = 0; t < 64; ++t) {
        float wv = wp[t];
        a0 += wv * xp[(size_t)t * 512 + tid];
        a1 += wv * xp[(size_t)t * 512 + tid + 256];
    }
    float* op = ctxp + (size_t)(b * 16 + tc) * 512;
    op[tid] = a0;
    op[tid + 256] = a1;
}

// context[b][d] = sum of 16 partials
__global__ void k_ctxred(const float* __restrict__ ctxp, float* __restrict__ ctx) {
    int idx = blockIdx.x * 256 + threadIdx.x;   // 8192
    int b = idx >> 9, d = idx & 511;
    float s = 0.f;
    #pragma unroll
    for (int p = 0; p < 16; ++p)
        s += ctxp[(size_t)(b * 16 + p) * 512 + d];
    ctx[b * 512 + d] = s;
}

// ---------------- launch ----------------
extern "C" void kernel_launch(void* const* d_in, const int* in_sizes, int n_in,
                              void* d_out, int out_size, void* d_ws, size_t ws_size,
                              hipStream_t stream) {
    (void)in_sizes; (void)n_in; (void)out_size; (void)ws_size;
    const float* x    = (const float*)d_in[0];
    const float* Went = (const float*)d_in[1];
    const float* bent = (const float*)d_in[2];
    const float* m1w  = (const float*)d_in[3];
    const float* m1b  = (const float*)d_in[4];
    const float* lng  = (const float*)d_in[5];
    const float* lnb  = (const float*)d_in[6];
    const float* m2w  = (const float*)d_in[7];
    const float* m2b  = (const float*)d_in[8];
    float* out = (float*)d_out;            // [0,8192): context ; [8192,24576): attn
    char* ws = (char*)d_ws;

    unsigned short* Abf   = (unsigned short*)(ws);                        // 4 MB
    unsigned short* WT    = (unsigned short*)(ws + 4194304);              // 8 MB
    float* CpL            = (float*)(ws + 12582912);                      // 8 MB
    float* CpR            = (float*)(ws + 20971520);                      // 8 MB
    unsigned short* ypk   = (unsigned short*)(ws + 12582912);             // 16 MB (reuses CpL/CpR after k_mid)
    unsigned short* M1bf  = (unsigned short*)(ws + 29360128);             // 512 KB
    unsigned short* M2t   = (unsigned short*)(ws + 29884416);             // 512 KB
    float* sumxp  = (float*)(ws + 30408704);                              // 512 KB
    float* ctxp   = (float*)(ws + 30932992);                              // 512 KB
    float* bias2  = (float*)(ws + 31457280);                              // 2 KB
    float* cb     = (float*)(ws + 31459328);                              // 32 KB
    float* logits = (float*)(ws + 31492096);                              // 64 KB

    k_pre<<<1792, 256, 0, stream>>>(x, m1w, bent, Went, sumxp, Abf, bias2, WT);
    k_gemm1<<<dim3(8, 4, 8), 512, 0, stream>>>(Abf, WT, CpL, CpR);
    k_mid<<<512, 256, 0, stream>>>(CpL, CpR, M1bf, M2t);
    k_cb<<<dim3(16, 8), 256, 0, stream>>>(sumxp, M2t, bias2, m1b, cb);
    k_gemm2s<<<dim3(512, 2), 256, 0, stream>>>(x, M1bf, ypk);
    k_lnlogit<<<512, 256, 0, stream>>>(ypk, cb, lng, lnb, m2w, m2b, logits);
    k_swctx<<<dim3(16, 16), 256, 0, stream>>>(x, logits, ctxp, out + 8192);
    k_ctxred<<<32, 256, 0, stream>>>(ctxp, out);
}